// Round 5
// baseline (713.757 us; speedup 1.0000x reference)
//
#include <hip/hip_runtime.h>

#define NN 16384      // nodes
#define NE 65536      // edges
#define H  32
#define BB 32
#define NPERB 512
#define NBLK 1024
#define NTHR 256
#define GS (NBLK * NTHR)   // 262144 threads

// ---- device-scope grid barrier (sense-free: one counter per phase) ----
__device__ __forceinline__ void grid_barrier(int* cnt) {
    __syncthreads();
    if (threadIdx.x == 0) {
        __hip_atomic_fetch_add(cnt, 1, __ATOMIC_RELEASE, __HIP_MEMORY_SCOPE_AGENT);
        while (__hip_atomic_load(cnt, __ATOMIC_RELAXED, __HIP_MEMORY_SCOPE_AGENT) < NBLK) {
            __builtin_amdgcn_s_sleep(2);
        }
    }
    __syncthreads();
    __builtin_amdgcn_fence(__ATOMIC_ACQUIRE, "agent");   // invalidate L1 view
}

__device__ __forceinline__ void layer_phase(
    int tid0, int base, const float* __restrict__ xin, float* __restrict__ xout,
    float* __restrict__ zb, const unsigned int* __restrict__ packed,
    const float* __restrict__ degf, const float* __restrict__ Wl,
    const float* __restrict__ Rl, const float* __restrict__ Bl, int relu_in) {
    // edge tasks: 2M lane-tasks, 8 exact grid-strides; 32 lanes per edge
#pragma unroll 1
    for (int k = 0; k < 8; ++k) {
        int t = tid0 + k * GS;
        int e = t >> 5, o = t & 31;
        unsigned int p = packed[e];          // broadcast within lane-group
        int s  = p & 16383;
        int d  = (p >> 14) & 16383;
        int ty = p >> 28;
        float xv = xin[s * H + o];           // coalesced 128B per half-wave
        if (relu_in) xv = fmaxf(xv, 0.f);
        float invd = __builtin_amdgcn_rcpf(fmaxf(degf[d], 1.0f));
        const float* __restrict__ W = Wl + ty * 1024 + o;
        float acc = 0.f;
#pragma unroll
        for (int i = 0; i < 32; ++i)
            acc = fmaf(__shfl(xv, base + i), W[i * 32], acc);
        atomicAdd(&xout[d * H + o], acc * invd);
    }
    // self tasks: out[n] += x[n]@root + b   (512K lane-tasks, 2 strides)
#pragma unroll 1
    for (int k = 0; k < 2; ++k) {
        int t2 = tid0 + k * GS;
        int o = t2 & 31;
        float xv = xin[t2];
        if (relu_in) xv = fmaxf(xv, 0.f);
        float acc = Bl[o];
#pragma unroll
        for (int i = 0; i < 32; ++i)
            acc = fmaf(__shfl(xv, base + i), Rl[i * 32 + o], acc);
        atomicAdd(&xout[t2], acc);
    }
    // zero next layer's accumulator
    if (zb) {
#pragma unroll 1
        for (int k = 0; k < 2; ++k)
            zb[tid0 + k * GS] = 0.f;
    }
}

__global__ __launch_bounds__(NTHR, 4) void k_all(
    const int* __restrict__ x_nodes, const int* __restrict__ edge_index,
    const int* __restrict__ edge_attr, const int* __restrict__ metal_idx,
    const int* __restrict__ loop_edge, const int* __restrict__ loop_pair,
    const float* __restrict__ node_emb, const float* __restrict__ edge_emb,
    const float* __restrict__ lin_w, const float* __restrict__ lin_b,
    const float* __restrict__ root_w, const float* __restrict__ conv_b,
    const float* __restrict__ f_w, const float* __restrict__ f_b,
    float* __restrict__ buf0, float* __restrict__ buf1, float* __restrict__ buf2,
    float* __restrict__ degf, int* __restrict__ bar,
    unsigned int* __restrict__ packed, float* __restrict__ Wt,
    float* __restrict__ out) {
    const int tid0 = blockIdx.x * NTHR + threadIdx.x;
    const int base = threadIdx.x & 32;       // half-wave base for shfl broadcast

    // ---- P0: embed + type-matrices + edge pack + deg hist + zero buf1 ----
#pragma unroll 1
    for (int k = 0; k < 2; ++k) {
        int t = tid0 + k * GS;
        buf0[t] = node_emb[x_nodes[t >> 5] * H + (t & 31)];
    }
    if (tid0 < 65536) {                      // w = l*16384 + ty*1024 + io
        int w = tid0;
        int l = w >> 14, rest = w & 16383;
        int ty = rest >> 10, io = rest & 1023;
        float acc = lin_b[l * 1024 + io];
#pragma unroll
        for (int j = 0; j < 8; ++j) {
            float e = edge_emb[(l * 16 + ty) * 8 + j];
            e = e > 0.f ? e : 0.f;
            acc = fmaf(e, lin_w[(l * 8 + j) * 1024 + io], acc);
        }
        Wt[w] = acc;
    } else if (tid0 < 131072) {
        int e = tid0 - 65536;
        unsigned int s  = (unsigned int)edge_index[e];
        unsigned int d  = (unsigned int)edge_index[NE + e];
        unsigned int ty = (unsigned int)edge_attr[e];
        packed[e] = s | (d << 14) | (ty << 28);
        atomicAdd(&degf[d], 1.0f);           // degf pre-zeroed by memset
    }
#pragma unroll 1
    for (int k = 0; k < 2; ++k)
        buf1[tid0 + k * GS] = 0.f;
    grid_barrier(&bar[0]);

    // ---- 4 layers; buffers rotate buf0->buf1->buf2->buf0->buf1 ----
    layer_phase(tid0, base, buf0, buf1, buf2, packed, degf,
                Wt + 0 * 16384, root_w + 0 * 1024, conv_b + 0 * H, 0);
    grid_barrier(&bar[1]);
    layer_phase(tid0, base, buf1, buf2, buf0, packed, degf,
                Wt + 1 * 16384, root_w + 1 * 1024, conv_b + 1 * H, 1);
    grid_barrier(&bar[2]);
    layer_phase(tid0, base, buf2, buf0, buf1, packed, degf,
                Wt + 2 * 16384, root_w + 2 * 1024, conv_b + 2 * H, 1);
    grid_barrier(&bar[3]);
    layer_phase(tid0, base, buf0, buf1, (float*)0, packed, degf,
                Wt + 3 * 16384, root_w + 3 * 1024, conv_b + 3 * H, 1);
    grid_barrier(&bar[4]);

    // ---- readout: B x 128 outputs from buf1 (layer-3 pre-activation) ----
    if (tid0 < BB * 128) {
        int b = tid0 >> 7, j = tid0 & 127;
        int mg = metal_idx[b] + b * NPERB;
        const float* __restrict__ xm = buf1 + mg * H;
        int p0, p1;
        if (j < 64) {
            p0 = loop_edge[(b * 64 + j) * 2];
            p1 = loop_edge[(b * 64 + j) * 2 + 1];
        } else {
            int j2 = j - 64;
            p0 = loop_pair[(b * 64 + j2) * 2];
            p1 = loop_pair[(b * 64 + j2) * 2 + 1];
        }
        const float* __restrict__ xs = buf1 + (b * NPERB + p0) * H;
        const float* __restrict__ xt = buf1 + (b * NPERB + p1) * H;
        float fh = f_b[0];
        float pp = 0.f;
#pragma unroll
        for (int h = 0; h < H; ++h) {
            float m = xm[h];
            fh = fmaf(m, f_w[h], fh);
            pp += m * (xs[h] + xt[h]) - xs[h] * xt[h];
        }
        out[tid0] = (j < 64) ? (pp - fh) : (-pp);
    }
}

extern "C" void kernel_launch(void* const* d_in, const int* in_sizes, int n_in,
                              void* d_out, int out_size, void* d_ws, size_t ws_size,
                              hipStream_t stream) {
    const int*   x_nodes    = (const int*)d_in[0];
    const int*   edge_index = (const int*)d_in[1];
    const int*   edge_attr  = (const int*)d_in[2];
    const int*   metal_idx  = (const int*)d_in[3];
    const int*   loop_edge  = (const int*)d_in[4];
    const int*   loop_pair  = (const int*)d_in[5];
    const float* node_emb   = (const float*)d_in[6];
    const float* edge_emb   = (const float*)d_in[7];
    const float* lin_w      = (const float*)d_in[8];
    const float* lin_b      = (const float*)d_in[9];
    const float* root_w     = (const float*)d_in[10];
    const float* conv_b     = (const float*)d_in[11];
    const float* f_w        = (const float*)d_in[12];
    const float* f_b        = (const float*)d_in[13];
    float* out = (float*)d_out;

    float* ws   = (float*)d_ws;
    float* buf0 = ws;                          // NN*H
    float* buf1 = buf0 + NN * H;               // NN*H
    float* buf2 = buf1 + NN * H;               // NN*H
    float* degf = buf2 + NN * H;               // NN      (zeroed)
    int*   bar  = (int*)(degf + NN);           // 16 ints (zeroed, contiguous)
    unsigned int* packed = (unsigned int*)(bar + 16);    // NE
    float* Wt   = (float*)(packed + NE);       // 4*16*1024

    // zero degf + barrier counters in one small fill
    hipMemsetAsync(degf, 0, (NN + 16) * sizeof(float), stream);

    k_all<<<NBLK, NTHR, 0, stream>>>(
        x_nodes, edge_index, edge_attr, metal_idx, loop_edge, loop_pair,
        node_emb, edge_emb, lin_w, lin_b, root_w, conv_b, f_w, f_b,
        buf0, buf1, buf2, degf, bar, packed, Wt, out);
}

// Round 6
// 185.754 us; speedup vs baseline: 3.8425x; 3.8425x over previous
//
#include <hip/hip_runtime.h>

#define NN 16384      // nodes
#define NE 65536      // edges
#define H  32
#define BB 32
#define NPERB 512

// ---- shared 32x32 matvec piece: lane j (of 8) accumulates output cols 4j..4j+3 ----
__device__ __forceinline__ void matvec8(const float* __restrict__ xrow,
                                        const float4* __restrict__ W4, int j,
                                        int relu_in, float4& acc) {
    const float4* __restrict__ xr4 = (const float4*)xrow;
    float4 a0 = xr4[0], a1 = xr4[1], a2 = xr4[2], a3 = xr4[3],
           a4 = xr4[4], a5 = xr4[5], a6 = xr4[6], a7 = xr4[7];
    float xr[32];
#define XC(k, v) xr[4*k+0]=v.x; xr[4*k+1]=v.y; xr[4*k+2]=v.z; xr[4*k+3]=v.w;
    XC(0,a0) XC(1,a1) XC(2,a2) XC(3,a3) XC(4,a4) XC(5,a5) XC(6,a6) XC(7,a7)
#undef XC
    if (relu_in) {
#pragma unroll
        for (int k = 0; k < 32; ++k) xr[k] = fmaxf(xr[k], 0.f);
    }
#pragma unroll
    for (int i = 0; i < 32; ++i) {
        float4 w = W4[i * 8 + j];          // same ty across wave -> one hot L1 line
        acc.x = fmaf(xr[i], w.x, acc.x);
        acc.y = fmaf(xr[i], w.y, acc.y);
        acc.z = fmaf(xr[i], w.z, acc.z);
        acc.w = fmaf(xr[i], w.w, acc.w);
    }
}

// ---- prep1: embed (f4) + type-matrices + deg hist + type hist + zero buf1 ----
__global__ __launch_bounds__(256) void k_prep1(
    const int* __restrict__ x_nodes, const int* __restrict__ edge_index,
    const int* __restrict__ edge_attr, const float* __restrict__ node_emb,
    const float* __restrict__ edge_emb, const float* __restrict__ lin_w,
    const float* __restrict__ lin_b, float* __restrict__ x0, float* __restrict__ Wt,
    float* __restrict__ degf, int* __restrict__ tcount, float* __restrict__ zb1) {
    __shared__ int lh[16];
    int b = blockIdx.x, thr = threadIdx.x;
    if (b < 512) {                          // embed: 131072 float4 tasks
        int t = b * 256 + thr;
        int n = t >> 3, r = t & 7;
        int xn = x_nodes[n];
        ((float4*)x0)[t] = ((const float4*)node_emb)[xn * 8 + r];
    } else if (b < 768) {                   // Wt: 65536 tasks (all 4 layers)
        int w = (b - 512) * 256 + thr;      // l*16384 + ty*1024 + io
        int l = w >> 14, rest = w & 16383;
        int ty = rest >> 10, io = rest & 1023;
        float acc = lin_b[l * 1024 + io];
#pragma unroll
        for (int jj = 0; jj < 8; ++jj) {
            float e2 = fmaxf(edge_emb[(l * 16 + ty) * 8 + jj], 0.f);
            acc = fmaf(e2, lin_w[(l * 8 + jj) * 1024 + io], acc);
        }
        Wt[w] = acc;
    } else if (b < 1024) {                  // edges: deg + type hist
        if (thr < 16) lh[thr] = 0;
        __syncthreads();
        int e = (b - 768) * 256 + thr;
        int d = edge_index[NE + e];
        int ty = edge_attr[e];
        atomicAdd(&degf[d], 1.0f);
        atomicAdd(&lh[ty], 1);
        __syncthreads();
        if (thr < 16) atomicAdd(&tcount[thr], lh[thr]);
    } else {                                // zero buf1: 131072 float4 tasks
        int z = (b - 1024) * 256 + thr;
        ((float4*)zb1)[z] = make_float4(0.f, 0.f, 0.f, 0.f);
    }
}

// ---- prep2: exclusive scan of 16 type counts -> bucket cursors ----
__global__ void k_prep2(const int* __restrict__ tcount, int* __restrict__ gcursor) {
    int t = threadIdx.x;
    int c = (t < 16) ? tcount[t] : 0;
    int base = 0;
    for (int u = 0; u < 15; ++u) {
        int cu = __shfl(c, u);
        if (u < t) base += cu;
    }
    if (t < 16) gcursor[t] = base;
}

// ---- prep3: counting-sort scatter into type buckets: blist[slot]=src|dst<<14|ty<<28 ----
__global__ __launch_bounds__(256) void k_prep3(
    const int* __restrict__ edge_index, const int* __restrict__ edge_attr,
    int* __restrict__ gcursor, unsigned int* __restrict__ blist) {
    __shared__ int lh[16], lb[16];
    int thr = threadIdx.x;
    if (thr < 16) lh[thr] = 0;
    __syncthreads();
    int e = blockIdx.x * 256 + thr;
    unsigned int s = (unsigned int)edge_index[e];
    unsigned int d = (unsigned int)edge_index[NE + e];
    int ty = edge_attr[e];
    int rank = atomicAdd(&lh[ty], 1);
    __syncthreads();
    if (thr < 16) lb[thr] = atomicAdd(&gcursor[thr], lh[thr]);
    __syncthreads();
    blist[lb[ty] + rank] = s | (d << 14) | ((unsigned int)ty << 28);
}

// ---- one layer: edge tasks (8 lanes/edge) + self tasks + zero next buffer ----
__global__ __launch_bounds__(256) void k_phase(
    const float* __restrict__ xin, float* __restrict__ xout, float* __restrict__ zb,
    const unsigned int* __restrict__ blist, const float* __restrict__ degf,
    const float* __restrict__ Wl, const float* __restrict__ Rl,
    const float* __restrict__ Bl, int relu_in) {
    int t = blockIdx.x * 256 + threadIdx.x;
    if (t < 524288) {                       // 64K edges x 8 lanes
        int e = t >> 3, j = t & 7;
        unsigned int p = blist[e];
        int s = p & 16383, d = (p >> 14) & 16383, ty = (int)(p >> 28);
        float4 acc = make_float4(0.f, 0.f, 0.f, 0.f);
        matvec8(xin + s * H, (const float4*)(Wl + ty * 1024), j, relu_in, acc);
        float invd = __builtin_amdgcn_rcpf(fmaxf(degf[d], 1.0f));
        float* o = xout + d * H + j * 4;
        atomicAdd(o + 0, acc.x * invd);
        atomicAdd(o + 1, acc.y * invd);
        atomicAdd(o + 2, acc.z * invd);
        atomicAdd(o + 3, acc.w * invd);
    } else if (t < 655360) {                // 16K nodes x 8 lanes: self term
        int t2 = t - 524288;
        int n = t2 >> 3, j = t2 & 7;
        float4 acc = ((const float4*)Bl)[j];
        matvec8(xin + n * H, (const float4*)Rl, j, relu_in, acc);
        float* o = xout + n * H + j * 4;
        atomicAdd(o + 0, acc.x);
        atomicAdd(o + 1, acc.y);
        atomicAdd(o + 2, acc.z);
        atomicAdd(o + 3, acc.w);
    } else if (zb) {                        // zero next accumulator (float4)
        ((float4*)zb)[t - 655360] = make_float4(0.f, 0.f, 0.f, 0.f);
    }
}

// ---- readout: one thread per output element (B x 128) ----
__global__ void k_final(const float* __restrict__ x, const int* __restrict__ metal_idx,
                        const int* __restrict__ loop_edge, const int* __restrict__ loop_pair,
                        const float* __restrict__ f_w, const float* __restrict__ f_b,
                        float* __restrict__ out) {
    int tid = blockIdx.x * blockDim.x + threadIdx.x;
    if (tid >= BB * 128) return;
    int b = tid >> 7, j = tid & 127;
    int mg = metal_idx[b] + b * NPERB;
    const float* __restrict__ xm = x + mg * H;
    int p0, p1;
    if (j < 64) {
        p0 = loop_edge[(b * 64 + j) * 2];
        p1 = loop_edge[(b * 64 + j) * 2 + 1];
    } else {
        int j2 = j - 64;
        p0 = loop_pair[(b * 64 + j2) * 2];
        p1 = loop_pair[(b * 64 + j2) * 2 + 1];
    }
    const float* __restrict__ xs = x + (b * NPERB + p0) * H;
    const float* __restrict__ xt = x + (b * NPERB + p1) * H;
    float fh = f_b[0];
    float pp = 0.f;
#pragma unroll
    for (int h = 0; h < H; ++h) {
        float m = xm[h];
        fh = fmaf(m, f_w[h], fh);
        pp += m * (xs[h] + xt[h]) - xs[h] * xt[h];
    }
    out[tid] = (j < 64) ? (pp - fh) : (-pp);
}

extern "C" void kernel_launch(void* const* d_in, const int* in_sizes, int n_in,
                              void* d_out, int out_size, void* d_ws, size_t ws_size,
                              hipStream_t stream) {
    const int*   x_nodes    = (const int*)d_in[0];
    const int*   edge_index = (const int*)d_in[1];
    const int*   edge_attr  = (const int*)d_in[2];
    const int*   metal_idx  = (const int*)d_in[3];
    const int*   loop_edge  = (const int*)d_in[4];
    const int*   loop_pair  = (const int*)d_in[5];
    const float* node_emb   = (const float*)d_in[6];
    const float* edge_emb   = (const float*)d_in[7];
    const float* lin_w      = (const float*)d_in[8];
    const float* lin_b      = (const float*)d_in[9];
    const float* root_w     = (const float*)d_in[10];
    const float* conv_b     = (const float*)d_in[11];
    const float* f_w        = (const float*)d_in[12];
    const float* f_b        = (const float*)d_in[13];
    float* out = (float*)d_out;

    float* ws   = (float*)d_ws;
    float* buf0 = ws;                          // 512K floats
    float* buf1 = buf0 + NN * H;               // 512K
    float* buf2 = buf1 + NN * H;               // 512K
    float* degf = buf2 + NN * H;               // NN       (zeroed)
    int*   tcount  = (int*)(degf + NN);        // 16       (zeroed)
    int*   gcursor = tcount + 16;              // 16       (zeroed)
    unsigned int* blist = (unsigned int*)(gcursor + 16);   // NE
    float* Wt   = (float*)(blist + NE);        // 4*16*1024

    // zero degf + tcount + gcursor in one small fill
    hipMemsetAsync(degf, 0, (NN + 32) * sizeof(float), stream);

    k_prep1<<<1536, 256, 0, stream>>>(x_nodes, edge_index, edge_attr, node_emb,
                                      edge_emb, lin_w, lin_b, buf0, Wt, degf, tcount, buf1);
    k_prep2<<<1, 64, 0, stream>>>(tcount, gcursor);
    k_prep3<<<256, 256, 0, stream>>>(edge_index, edge_attr, gcursor, blist);

    // rotation: buf0->buf1 (zero buf2), buf1->buf2 (zero buf0),
    //           buf2->buf0 (zero buf1), buf0->buf1 (no zero). final reads buf1.
    k_phase<<<3072, 256, 0, stream>>>(buf0, buf1, buf2, blist, degf,
                                      Wt + 0 * 16384, root_w + 0 * 1024, conv_b + 0 * H, 0);
    k_phase<<<3072, 256, 0, stream>>>(buf1, buf2, buf0, blist, degf,
                                      Wt + 1 * 16384, root_w + 1 * 1024, conv_b + 1 * H, 1);
    k_phase<<<3072, 256, 0, stream>>>(buf2, buf0, buf1, blist, degf,
                                      Wt + 2 * 16384, root_w + 2 * 1024, conv_b + 2 * H, 1);
    k_phase<<<2560, 256, 0, stream>>>(buf0, buf1, (float*)0, blist, degf,
                                      Wt + 3 * 16384, root_w + 3 * 1024, conv_b + 3 * H, 1);

    k_final<<<16, 256, 0, stream>>>(buf1, metal_idx, loop_edge, loop_pair, f_w, f_b, out);
}

// Round 7
// 94.655 us; speedup vs baseline: 7.5406x; 1.9624x over previous
//
#include <hip/hip_runtime.h>

#define NN 16384      // nodes
#define NE 65536      // edges
#define H  32
#define BB 32
#define NPERB 512

// ---- prep1: embed (f4) + type-matrices + deg hist + type hist + zero buf1 ----
__global__ __launch_bounds__(256) void k_prep1(
    const int* __restrict__ x_nodes, const int* __restrict__ edge_index,
    const int* __restrict__ edge_attr, const float* __restrict__ node_emb,
    const float* __restrict__ edge_emb, const float* __restrict__ lin_w,
    const float* __restrict__ lin_b, float* __restrict__ x0, float* __restrict__ Wt,
    float* __restrict__ degf, int* __restrict__ tcount, float* __restrict__ zb1) {
    __shared__ int lh[16];
    int b = blockIdx.x, thr = threadIdx.x;
    if (b < 512) {                          // embed: 131072 float4 tasks
        int t = b * 256 + thr;
        int n = t >> 3, r = t & 7;
        int xn = x_nodes[n];
        ((float4*)x0)[t] = ((const float4*)node_emb)[xn * 8 + r];
    } else if (b < 768) {                   // Wt: 65536 tasks (all 4 layers)
        int w = (b - 512) * 256 + thr;      // l*16384 + ty*1024 + io
        int l = w >> 14, rest = w & 16383;
        int ty = rest >> 10, io = rest & 1023;
        float acc = lin_b[l * 1024 + io];
#pragma unroll
        for (int jj = 0; jj < 8; ++jj) {
            float e2 = fmaxf(edge_emb[(l * 16 + ty) * 8 + jj], 0.f);
            acc = fmaf(e2, lin_w[(l * 8 + jj) * 1024 + io], acc);
        }
        Wt[w] = acc;
    } else if (b < 1024) {                  // edges: deg + type hist
        if (thr < 16) lh[thr] = 0;
        __syncthreads();
        int e = (b - 768) * 256 + thr;
        int d = edge_index[NE + e];
        int ty = edge_attr[e];
        atomicAdd(&degf[d], 1.0f);
        atomicAdd(&lh[ty], 1);
        __syncthreads();
        if (thr < 16) atomicAdd(&tcount[thr], lh[thr]);
    } else {                                // zero buf1: 131072 float4 tasks
        int z = (b - 1024) * 256 + thr;
        ((float4*)zb1)[z] = make_float4(0.f, 0.f, 0.f, 0.f);
    }
}

// ---- prep2: exclusive scan of 16 type counts -> bucket cursors ----
__global__ void k_prep2(const int* __restrict__ tcount, int* __restrict__ gcursor) {
    int t = threadIdx.x;
    int c = (t < 16) ? tcount[t] : 0;
    int base = 0;
    for (int u = 0; u < 15; ++u) {
        int cu = __shfl(c, u);
        if (u < t) base += cu;
    }
    if (t < 16) gcursor[t] = base;
}

// ---- prep3: counting-sort scatter into type buckets: blist[slot]=src|dst<<14|ty<<28 ----
__global__ __launch_bounds__(256) void k_prep3(
    const int* __restrict__ edge_index, const int* __restrict__ edge_attr,
    int* __restrict__ gcursor, unsigned int* __restrict__ blist) {
    __shared__ int lh[16], lb[16];
    int thr = threadIdx.x;
    if (thr < 16) lh[thr] = 0;
    __syncthreads();
    int e = blockIdx.x * 256 + thr;
    unsigned int s = (unsigned int)edge_index[e];
    unsigned int d = (unsigned int)edge_index[NE + e];
    int ty = edge_attr[e];
    int rank = atomicAdd(&lh[ty], 1);
    __syncthreads();
    if (thr < 16) lb[thr] = atomicAdd(&gcursor[thr], lh[thr]);
    __syncthreads();
    blist[lb[ty] + rank] = s | (d << 14) | ((unsigned int)ty << 28);
}

// ---- one layer: edge tasks (32 lanes/edge, shfl broadcast, wave-contiguous atomics)
//      + self tasks + zero next buffer ----
__global__ __launch_bounds__(256) void k_phase(
    const float* __restrict__ xin, float* __restrict__ xout, float* __restrict__ zb,
    const unsigned int* __restrict__ blist, const float* __restrict__ degf,
    const float* __restrict__ Wl, const float* __restrict__ Rl,
    const float* __restrict__ Bl, int relu_in) {
    int t = blockIdx.x * 256 + threadIdx.x;
    int base = threadIdx.x & 32;            // half-wave base for shfl broadcast
    if (t < 2097152) {                      // 64K edges x 32 lanes
        int e = t >> 5, o = t & 31;
        unsigned int p = blist[e];          // sorted by type -> wave-uniform ty
        int s = p & 16383, d = (p >> 14) & 16383, ty = (int)(p >> 28);
        float xv = xin[s * H + o];          // coalesced 128B per half-wave
        if (relu_in) xv = fmaxf(xv, 0.f);
        float invd = __builtin_amdgcn_rcpf(fmaxf(degf[d], 1.0f));
        const float* __restrict__ W = Wl + ty * 1024 + o;
        float acc = 0.f;
#pragma unroll
        for (int i = 0; i < 32; ++i)        // W[i*32+o]: one hot 128B L1 line per i
            acc = fmaf(__shfl(xv, base + i), W[i * 32], acc);
        atomicAdd(&xout[d * H + o], acc * invd);   // 32 lanes -> one contiguous row
    } else if (t < 2621440) {               // self: out[n] += x[n]@root + b
        int t2 = t - 2097152;
        int o = t2 & 31;
        float xv = xin[t2];
        if (relu_in) xv = fmaxf(xv, 0.f);
        float acc = Bl[o];
#pragma unroll
        for (int i = 0; i < 32; ++i)
            acc = fmaf(__shfl(xv, base + i), Rl[i * 32 + o], acc);
        atomicAdd(&xout[t2], acc);
    } else if (zb) {                        // zero next accumulator
        zb[t - 2621440] = 0.f;
    }
}

// ---- readout: one thread per output element (B x 128) ----
__global__ void k_final(const float* __restrict__ x, const int* __restrict__ metal_idx,
                        const int* __restrict__ loop_edge, const int* __restrict__ loop_pair,
                        const float* __restrict__ f_w, const float* __restrict__ f_b,
                        float* __restrict__ out) {
    int tid = blockIdx.x * blockDim.x + threadIdx.x;
    if (tid >= BB * 128) return;
    int b = tid >> 7, j = tid & 127;
    int mg = metal_idx[b] + b * NPERB;
    const float* __restrict__ xm = x + mg * H;
    int p0, p1;
    if (j < 64) {
        p0 = loop_edge[(b * 64 + j) * 2];
        p1 = loop_edge[(b * 64 + j) * 2 + 1];
    } else {
        int j2 = j - 64;
        p0 = loop_pair[(b * 64 + j2) * 2];
        p1 = loop_pair[(b * 64 + j2) * 2 + 1];
    }
    const float* __restrict__ xs = x + (b * NPERB + p0) * H;
    const float* __restrict__ xt = x + (b * NPERB + p1) * H;
    float fh = f_b[0];
    float pp = 0.f;
#pragma unroll
    for (int h = 0; h < H; ++h) {
        float m = xm[h];
        fh = fmaf(m, f_w[h], fh);
        pp += m * (xs[h] + xt[h]) - xs[h] * xt[h];
    }
    out[tid] = (j < 64) ? (pp - fh) : (-pp);
}

extern "C" void kernel_launch(void* const* d_in, const int* in_sizes, int n_in,
                              void* d_out, int out_size, void* d_ws, size_t ws_size,
                              hipStream_t stream) {
    const int*   x_nodes    = (const int*)d_in[0];
    const int*   edge_index = (const int*)d_in[1];
    const int*   edge_attr  = (const int*)d_in[2];
    const int*   metal_idx  = (const int*)d_in[3];
    const int*   loop_edge  = (const int*)d_in[4];
    const int*   loop_pair  = (const int*)d_in[5];
    const float* node_emb   = (const float*)d_in[6];
    const float* edge_emb   = (const float*)d_in[7];
    const float* lin_w      = (const float*)d_in[8];
    const float* lin_b      = (const float*)d_in[9];
    const float* root_w     = (const float*)d_in[10];
    const float* conv_b     = (const float*)d_in[11];
    const float* f_w        = (const float*)d_in[12];
    const float* f_b        = (const float*)d_in[13];
    float* out = (float*)d_out;

    float* ws   = (float*)d_ws;
    float* buf0 = ws;                          // 512K floats
    float* buf1 = buf0 + NN * H;               // 512K
    float* buf2 = buf1 + NN * H;               // 512K
    float* degf = buf2 + NN * H;               // NN       (zeroed)
    int*   tcount  = (int*)(degf + NN);        // 16       (zeroed)
    int*   gcursor = tcount + 16;              // 16       (zeroed)
    unsigned int* blist = (unsigned int*)(gcursor + 16);   // NE
    float* Wt   = (float*)(blist + NE);        // 4*16*1024

    // zero degf + tcount + gcursor in one small fill
    hipMemsetAsync(degf, 0, (NN + 32) * sizeof(float), stream);

    k_prep1<<<1536, 256, 0, stream>>>(x_nodes, edge_index, edge_attr, node_emb,
                                      edge_emb, lin_w, lin_b, buf0, Wt, degf, tcount, buf1);
    k_prep2<<<1, 64, 0, stream>>>(tcount, gcursor);
    k_prep3<<<256, 256, 0, stream>>>(edge_index, edge_attr, gcursor, blist);

    // rotation: buf0->buf1 (zero buf2), buf1->buf2 (zero buf0),
    //           buf2->buf0 (zero buf1), buf0->buf1 (no zero). final reads buf1.
    k_phase<<<12288, 256, 0, stream>>>(buf0, buf1, buf2, blist, degf,
                                       Wt + 0 * 16384, root_w + 0 * 1024, conv_b + 0 * H, 0);
    k_phase<<<12288, 256, 0, stream>>>(buf1, buf2, buf0, blist, degf,
                                       Wt + 1 * 16384, root_w + 1 * 1024, conv_b + 1 * H, 1);
    k_phase<<<12288, 256, 0, stream>>>(buf2, buf0, buf1, blist, degf,
                                       Wt + 2 * 16384, root_w + 2 * 1024, conv_b + 2 * H, 1);
    k_phase<<<10240, 256, 0, stream>>>(buf0, buf1, (float*)0, blist, degf,
                                       Wt + 3 * 16384, root_w + 3 * 1024, conv_b + 3 * H, 1);

    k_final<<<16, 256, 0, stream>>>(buf1, metal_idx, loop_edge, loop_pair, f_w, f_b, out);
}